// Round 23
// baseline (178.061 us; speedup 1.0000x reference)
//
#include <hip/hip_runtime.h>
#include <hip/hip_bf16.h>

#define D_MODEL 96
#define D_INNER 192
#define BATCH 32
#define HH 56
#define WW 56
#define NPIX (BATCH*HH*WW)   // 100352
#define LN_EPS 1e-5f
#define K2_NWG 1568          // NPIX / 64 = 8 * 196 (bijective XCD swizzle)
#define K2_CPX 196

typedef unsigned short ushort_t;
typedef __attribute__((ext_vector_type(8))) short short8;   // 8 bf16 (4 VGPRs)
typedef __attribute__((ext_vector_type(4))) float f32x4;

// g_Wt: conv weights [tap][oc][ic] bf16 PLAIN layout (r2-verified).
// g_Wit: in_proj live-half [oc][ic] bf16.
__device__ __align__(16) ushort_t g_Wt[9 * 96 * 192];
__device__ __align__(16) ushort_t g_Wit[192 * 96];

static __device__ __forceinline__ unsigned short f2bf(float f) {
    unsigned u = __float_as_uint(f);
    unsigned r = (u + 0x7fffu + ((u >> 16) & 1u)) >> 16;
    return (unsigned short)r;
}

// ---------------------------------------------------------------------------
// Kernel 0: weight prep (byte-identical to r22, verified).
// ---------------------------------------------------------------------------
__global__ __launch_bounds__(256) void k0_wt(const float* __restrict__ Wc,
                                             const float* __restrict__ Wi) {
    const int o = blockIdx.x * 256 + threadIdx.x;
    if (o < 9 * 18432) {
        const int tap = o / 18432;
        const int rem = o - tap * 18432;
        const int oc = rem / 192;
        const int ic = rem - oc * 192;
        g_Wt[o] = f2bf(Wc[(tap * 192 + ic) * 96 + oc]);
    }
    if (o < 192 * 96) {
        const int oc = o / 96, ic = o - oc * 96;
        g_Wit[o] = f2bf(Wi[ic * 384 + oc]);
    }
}

// ---------------------------------------------------------------------------
// Kernel 1: LayerNorm + in_projection (byte-identical to r21/r22, verified):
// X1 stores pre-swizzled per pixel (byte ^= ((pix&7)<<4)).
// ---------------------------------------------------------------------------
__global__ __launch_bounds__(256) void k1_ln_proj(
    const float* __restrict__ X, const float* __restrict__ ln_w,
    const float* __restrict__ ln_b, const float* __restrict__ b_in,
    ushort_t* __restrict__ X1)
{
    __shared__ ushort_t sH[64 * 104];
    __shared__ ushort_t sO[64 * 200];
    const int t = threadIdx.x;

    const int g = t >> 2, tig = t & 3;
    const int pix = blockIdx.x * 64 + g;
    const float* xp = X + (size_t)pix * 96 + tig * 24;
    float4 xq[6];
    float s = 0.f;
    #pragma unroll
    for (int c = 0; c < 6; ++c) {
        xq[c] = *(const float4*)(xp + c * 4);
        s += xq[c].x + xq[c].y + xq[c].z + xq[c].w;
    }
    s += __shfl_xor(s, 1, 4);
    s += __shfl_xor(s, 2, 4);
    const float mu = s * (1.f / 96.f);
    float v = 0.f;
    #pragma unroll
    for (int c = 0; c < 6; ++c) {
        const float d0 = xq[c].x - mu, d1 = xq[c].y - mu;
        const float d2 = xq[c].z - mu, d3 = xq[c].w - mu;
        v += d0 * d0 + d1 * d1 + d2 * d2 + d3 * d3;
    }
    v += __shfl_xor(v, 1, 4);
    v += __shfl_xor(v, 2, 4);
    const float rs = rsqrtf(v * (1.f / 96.f) + LN_EPS);
    #pragma unroll
    for (int c = 0; c < 6; ++c) {
        const float4 lw = *(const float4*)(ln_w + tig * 24 + c * 4);
        const float4 lb = *(const float4*)(ln_b + tig * 24 + c * 4);
        const unsigned p0 = (unsigned)f2bf((xq[c].x - mu) * rs * lw.x + lb.x)
                          | ((unsigned)f2bf((xq[c].y - mu) * rs * lw.y + lb.y) << 16);
        const unsigned p1 = (unsigned)f2bf((xq[c].z - mu) * rs * lw.z + lb.z)
                          | ((unsigned)f2bf((xq[c].w - mu) * rs * lw.w + lb.w) << 16);
        uint2 u; u.x = p0; u.y = p1;
        *(uint2*)&sH[g * 104 + tig * 24 + c * 4] = u;
    }
    __syncthreads();

    const int w = t >> 6, l = t & 63;
    const int lm = l & 15, lq = l >> 4;
    const ushort_t* hp = &sH[(w * 16 + lm) * 104 + lq * 8];

    f32x4 acc[12];
    const f32x4 zf = {0.f, 0.f, 0.f, 0.f};
    #pragma unroll
    for (int mt = 0; mt < 12; ++mt) acc[mt] = zf;

    #pragma unroll
    for (int kk = 0; kk < 3; ++kk) {
        const short8 hb = *(const short8*)(hp + kk * 32);
        #pragma unroll
        for (int mt = 0; mt < 12; ++mt) {
            const short8 wa = *(const short8*)(g_Wit + (mt * 16 + lm) * 96 + kk * 32 + lq * 8);
            acc[mt] = __builtin_amdgcn_mfma_f32_16x16x32_bf16(wa, hb, acc[mt], 0, 0, 0);
        }
    }

    #pragma unroll
    for (int mt = 0; mt < 12; ++mt) {
        const int oc0 = mt * 16 + lq * 4;
        const float4 bv = *(const float4*)(b_in + oc0);
        uint2 u;
        u.x = (unsigned)f2bf(acc[mt][0] + bv.x) | ((unsigned)f2bf(acc[mt][1] + bv.y) << 16);
        u.y = (unsigned)f2bf(acc[mt][2] + bv.z) | ((unsigned)f2bf(acc[mt][3] + bv.w) << 16);
        *(uint2*)&sO[(w * 16 + lm) * 200 + oc0] = u;
    }
    __syncthreads();

    const char* sOb = (const char*)sO + w * 16 * 400;
    char* gdst = (char*)X1 + (size_t)(blockIdx.x * 64 + w * 16) * 384;
    #pragma unroll
    for (int c = 0; c < 6; ++c) {
        const int gb = c * 1024 + l * 16;
        const int px = gb / 384, b = gb - px * 384;
        const uint4 val = *(const uint4*)(sOb + px * 400 + b);
        *(uint4*)(gdst + (gb ^ ((px & 7) << 4))) = val;
    }
}

// ---------------------------------------------------------------------------
// Kernel 2 (template): SKEL=0 is byte-identical to the r22 kernel (verified
// 100.9 us). SKEL=1 is the measurement variant: A and B replaced by
// load-once constants; halo staging, MFMA chain, and epilogue UNCHANGED
// (same LDS, same occupancy regime). Skeleton time = total - 133.1.
// ---------------------------------------------------------------------------
template<int SKEL>
__global__ __launch_bounds__(128) void k2_t(
    const ushort_t* __restrict__ X1, const float* __restrict__ conv_b,
    const float* __restrict__ X, float* __restrict__ OUT)
{
    __shared__ ushort_t sX[100 * 192];   // 38,400 B halo (pre-swizzled blocks)
    const int t = threadIdx.x;
    const int w = t >> 6, l = t & 63;
    const int lm = l & 15, lq = l >> 4;

    const int lb = ((int)blockIdx.x & 7) * K2_CPX + ((int)blockIdx.x >> 3);
    const int img = lb / 49, tile = lb - img * 49;
    const int ty = (tile / 7) * 8, tx = (tile % 7) * 8;
    const size_t imgbase = (size_t)img * 3136 * 192;

    // ---- stage halo: verbatim copies (swizzle travels with the data) ----
    for (int idx = t; idx < 2400; idx += 128) {       // 100 px * 24 uint4
        const int hp2 = idx / 24, q = idx - hp2 * 24;
        const int hr = hp2 / 10, hc = hp2 - hr * 10;
        const int gr = ty + hr - 1, gc = tx + hc - 1;
        uint4 val = make_uint4(0u, 0u, 0u, 0u);
        if (gr >= 0 && gr < HH && gc >= 0 && gc < WW)
            val = *(const uint4*)(X1 + imgbase + (size_t)(gr * WW + gc) * 192 + q * 8);
        *(uint4*)&sX[hp2 * 192 + q * 8] = val;
    }

    const ushort_t* bbase = g_Wt + (size_t)(w * 48 + lm) * 192 + lq * 8;
    auto loadB9 = [&](short8 (&buf)[9], int tap, int half) {
        const ushort_t* p = bbase + tap * 18432 + half * 96;
        #pragma unroll
        for (int n = 0; n < 3; ++n)
            #pragma unroll
            for (int k2 = 0; k2 < 3; ++k2)
                buf[n * 3 + k2] = *(const short8*)(p + n * 3072 + k2 * 32);
    };

    int pr[4], pc[4];
    #pragma unroll
    for (int i = 0; i < 4; ++i) {
        const int px = i * 16 + lm;
        pr[i] = px >> 3; pc[i] = px & 7;
    }

    f32x4 acc[4][3];
    const f32x4 zf = {0.f, 0.f, 0.f, 0.f};
    #pragma unroll
    for (int i = 0; i < 4; ++i)
        #pragma unroll
        for (int n = 0; n < 3; ++n) acc[i][n] = zf;

    if constexpr (SKEL) {
        // ---- skeleton: load-once constant operands; MFMA chain + epilogue
        //      structure identical; zero per-iteration loads. ----
        __syncthreads();
        const short8 a_const = *(const short8*)(sX + (size_t)l * 8);
        const short8 b_const = *(const short8*)(g_Wt + (size_t)l * 8);
        #pragma unroll 1
        for (int tap = 0; tap < 9; ++tap) {
            #pragma unroll
            for (int kk = 0; kk < 6; ++kk)
                #pragma unroll
                for (int i = 0; i < 4; ++i)
                    #pragma unroll
                    for (int n = 0; n < 3; ++n)
                        acc[i][n] = __builtin_amdgcn_mfma_f32_16x16x32_bf16(
                            a_const, b_const, acc[i][n], 0, 0, 0);
        }
        __syncthreads();
    } else {
        short8 bL[9], bH[9];
        loadB9(bL, 0, 0);
        __syncthreads();

        #pragma unroll 1
        for (int tap = 0; tap < 9; ++tap) {
            const int ky = tap / 3, kx = tap - (tap / 3) * 3;
            int abyte[4], akey[4];
            #pragma unroll
            for (int i = 0; i < 4; ++i) {
                abyte[i] = ((pr[i] + ky) * 10 + pc[i] + kx) * 384;
                akey[i] = ((tx + pc[i] + kx - 1) & 7) << 4;
            }

            loadB9(bH, tap, 1);
            #pragma unroll
            for (int k2 = 0; k2 < 3; ++k2) {
                const int kk = k2;
                short8 a[4];
                #pragma unroll
                for (int i = 0; i < 4; ++i) {
                    const int s = (kk * 64 + lq * 16) ^ akey[i];
                    a[i] = *(const short8*)((const char*)sX + abyte[i] + s);
                }
                #pragma unroll
                for (int i = 0; i < 4; ++i)
                    #pragma unroll
                    for (int n = 0; n < 3; ++n)
                        acc[i][n] = __builtin_amdgcn_mfma_f32_16x16x32_bf16(
                            a[i], bL[n * 3 + k2], acc[i][n], 0, 0, 0);
            }

            if (tap < 8) loadB9(bL, tap + 1, 0);
            #pragma unroll
            for (int k2 = 0; k2 < 3; ++k2) {
                const int kk = 3 + k2;
                short8 a[4];
                #pragma unroll
                for (int i = 0; i < 4; ++i) {
                    const int s = (kk * 64 + lq * 16) ^ akey[i];
                    a[i] = *(const short8*)((const char*)sX + abyte[i] + s);
                }
                #pragma unroll
                for (int i = 0; i < 4; ++i)
                    #pragma unroll
                    for (int n = 0; n < 3; ++n)
                        acc[i][n] = __builtin_amdgcn_mfma_f32_16x16x32_bf16(
                            a[i], bH[n * 3 + k2], acc[i][n], 0, 0, 0);
            }
        }
        __syncthreads();
    }

    // ---- epilogue: silu via LDS transpose (sX dead), coalesced stores ----
    float* sY = (float*)sX;
    float bvn[3];
    #pragma unroll
    for (int n = 0; n < 3; ++n) bvn[n] = conv_b[w * 48 + n * 16 + lm];

    #pragma unroll
    for (int i = 0; i < 4; ++i)
        #pragma unroll
        for (int n = 0; n < 3; ++n)
            #pragma unroll
            for (int r4 = 0; r4 < 4; ++r4) {
                const float y = acc[i][n][r4] + bvn[n];
                const float sig = 1.f / (1.f + __expf(-y));
                sY[(i * 16 + lq * 4 + r4) * 100 + w * 48 + n * 16 + lm] = y * sig;
            }
    __syncthreads();

    #pragma unroll
    for (int c = 0; c < 12; ++c) {
        const int d = c * 512 + t * 4;
        const int px = d / 96, b = d - px * 96;
        const int grow = ty + (px >> 3), gcol = tx + (px & 7);
        const size_t gdw = ((size_t)img * 3136 + grow * 56 + gcol) * 96 + b;
        const f32x4 yv = *(const f32x4*)(sY + px * 100 + b);
        const float4 xv = *(const float4*)(X + gdw);
        float4 o;
        o.x = xv.x + yv[0]; o.y = xv.y + yv[1];
        o.z = xv.z + yv[2]; o.w = xv.w + yv[3];
        *(float4*)(OUT + gdw) = o;
    }
}

extern "C" void kernel_launch(void* const* d_in, const int* in_sizes, int n_in,
                              void* d_out, int out_size, void* d_ws, size_t ws_size,
                              hipStream_t stream) {
    (void)in_sizes; (void)n_in; (void)out_size; (void)ws_size;
    const float* X    = (const float*)d_in[0];
    const float* ln_w = (const float*)d_in[1];
    const float* ln_b = (const float*)d_in[2];
    const float* Wi   = (const float*)d_in[3];
    const float* b_in = (const float*)d_in[4];
    const float* Wc   = (const float*)d_in[5];
    const float* cb   = (const float*)d_in[6];
    float* OUT = (float*)d_out;
    ushort_t* X1 = (ushort_t*)d_ws;   // 100352*192 bf16 = 38.5 MB (pre-swizzled)

    k0_wt<<<(9 * 96 * 192 + 255) / 256, 256, 0, stream>>>(Wc, Wi);
    k1_ln_proj<<<NPIX / 64, 256, 0, stream>>>(X, ln_w, ln_b, b_in, X1);
    k2_t<1><<<K2_NWG, 128, 0, stream>>>(X1, cb, X, OUT);   // skeleton (measured via total)
    k2_t<0><<<K2_NWG, 128, 0, stream>>>(X1, cb, X, OUT);   // FULL (correct output)
}

// Round 25
// 143.013 us; speedup vs baseline: 1.2451x; 1.2451x over previous
//
#include <hip/hip_runtime.h>
#include <hip/hip_bf16.h>

#define D_MODEL 96
#define D_INNER 192
#define BATCH 32
#define HH 56
#define WW 56
#define NPIX (BATCH*HH*WW)   // 100352
#define LN_EPS 1e-5f
#define K2_NWG 1568          // NPIX / 64 = 8 * 196 (bijective XCD swizzle)
#define K2_CPX 196

typedef unsigned short ushort_t;
typedef __attribute__((ext_vector_type(8))) short short8;   // 8 bf16 (4 VGPRs)
typedef __attribute__((ext_vector_type(4))) float f32x4;

// g_Wt: conv weights [tap][oc][ic] bf16 PLAIN (r2/r22-verified).
// g_Wit: in_proj live-half [oc=192][ic=96] bf16 (r9-verified).
__device__ __align__(16) ushort_t g_Wt[9 * 96 * 192];
__device__ __align__(16) ushort_t g_Wit[192 * 96];

static __device__ __forceinline__ unsigned short f2bf(float f) {
    unsigned u = __float_as_uint(f);
    unsigned r = (u + 0x7fffu + ((u >> 16) & 1u)) >> 16;
    return (unsigned short)r;
}

// ---------------------------------------------------------------------------
// Kernel 0: weight prep (byte-identical to r22, verified).
// ---------------------------------------------------------------------------
__global__ __launch_bounds__(256) void k0_wt(const float* __restrict__ Wc,
                                             const float* __restrict__ Wi) {
    const int o = blockIdx.x * 256 + threadIdx.x;
    if (o < 9 * 18432) {
        const int tap = o / 18432;
        const int rem = o - tap * 18432;
        const int oc = rem / 192;
        const int ic = rem - oc * 192;
        g_Wt[o] = f2bf(Wc[(tap * 192 + ic) * 96 + oc]);
    }
    if (o < 192 * 96) {
        const int oc = o / 96, ic = o - oc * 96;
        g_Wit[o] = f2bf(Wi[ic * 384 + oc]);
    }
}

// ---------------------------------------------------------------------------
// FUSED kernel: LN + in_proj (halo recompute) + 3x3 conv + SiLU + residual.
// ROUND-25 = round-24 with ONE fix: Phase-2 store guarded by (hp < 100).
// r24's pad slots hp in [100,112) stored at boff >= 38,400 — past the end
// of sX1, landing in sH (when sX1 precedes sH in LDS layout) and corrupting
// h rows 0-22 mid-phase -> absmax 2.5. Pad D-values were already discarded;
// now the store is too. Everything else byte-identical to r24.
// ---------------------------------------------------------------------------
__global__ __launch_bounds__(128) void k_fused(
    const float* __restrict__ X, const float* __restrict__ ln_w,
    const float* __restrict__ ln_b, const float* __restrict__ b_in,
    const float* __restrict__ conv_b, float* __restrict__ OUT)
{
    __shared__ ushort_t sH[112 * 104];    // 23,296 B (bf16 h, halo+pad)
    __shared__ ushort_t sX1[100 * 192];   // 38,400 B (pre-swizzled x1 halo)
    const int t = threadIdx.x;
    const int w = t >> 6, l = t & 63;
    const int lm = l & 15, lq = l >> 4;

    const int lb = ((int)blockIdx.x & 7) * K2_CPX + ((int)blockIdx.x >> 3);
    const int img = lb / 49, tile = lb - img * 49;
    const int ty = (tile / 7) * 8, tx = (tile % 7) * 8;
    const size_t imgbase96 = (size_t)img * 3136 * 96;

    // ================= Phase 1: LayerNorm (4 threads / pixel) =============
    {
        const int g4 = t >> 2, tig = t & 3;
        #pragma unroll 1
        for (int it = 0; it < 4; ++it) {
            const int hp = it * 32 + g4;
            if (hp >= 112) continue;
            const int hr = hp / 10, hc = hp - hr * 10;
            const int gr = ty + hr - 1, gc = tx + hc - 1;
            const bool valid = (hp < 100) && gr >= 0 && gr < HH && gc >= 0 && gc < WW;
            const float* xp = X + imgbase96 + (size_t)(gr * WW + gc) * 96 + tig * 24;
            float4 xq[6];
            float s = 0.f;
            #pragma unroll
            for (int c = 0; c < 6; ++c) {
                xq[c] = valid ? *(const float4*)(xp + c * 4)
                              : make_float4(0.f, 0.f, 0.f, 0.f);
                s += xq[c].x + xq[c].y + xq[c].z + xq[c].w;
            }
            s += __shfl_xor(s, 1, 4);
            s += __shfl_xor(s, 2, 4);
            const float mu = s * (1.f / 96.f);
            float v = 0.f;
            #pragma unroll
            for (int c = 0; c < 6; ++c) {
                const float d0 = xq[c].x - mu, d1 = xq[c].y - mu;
                const float d2 = xq[c].z - mu, d3 = xq[c].w - mu;
                v += d0 * d0 + d1 * d1 + d2 * d2 + d3 * d3;
            }
            v += __shfl_xor(v, 1, 4);
            v += __shfl_xor(v, 2, 4);
            const float rs = rsqrtf(v * (1.f / 96.f) + LN_EPS);
            #pragma unroll
            for (int c = 0; c < 6; ++c) {
                const float4 lw = *(const float4*)(ln_w + tig * 24 + c * 4);
                const float4 lb2 = *(const float4*)(ln_b + tig * 24 + c * 4);
                const unsigned p0 = (unsigned)f2bf((xq[c].x - mu) * rs * lw.x + lb2.x)
                                  | ((unsigned)f2bf((xq[c].y - mu) * rs * lw.y + lb2.y) << 16);
                const unsigned p1 = (unsigned)f2bf((xq[c].z - mu) * rs * lw.z + lb2.z)
                                  | ((unsigned)f2bf((xq[c].w - mu) * rs * lw.w + lb2.w) << 16);
                uint2 u; u.x = p0; u.y = p1;
                *(uint2*)&sH[hp * 104 + tig * 24 + c * 4] = u;
            }
        }
    }
    __syncthreads();

    // ===== Phase 2: proj h(96) -> x1(192), pre-swizzled into sX1 ==========
    // wave w owns channels [w*96, w*96+96) = 6 ch-tiles; px-tiles nt 0..6.
    {
        #pragma unroll 1
        for (int mt = 0; mt < 6; ++mt) {
            const int ct = w * 6 + mt;                 // ch-tile 0..11
            short8 wa[3];
            #pragma unroll
            for (int kk = 0; kk < 3; ++kk)
                wa[kk] = *(const short8*)(g_Wit + (ct * 16 + lm) * 96 + kk * 32 + lq * 8);
            const float4 bv = *(const float4*)(b_in + ct * 16 + lq * 4);

            #pragma unroll 1
            for (int nt = 0; nt < 7; ++nt) {
                const int hp = nt * 16 + lm;           // this lane's pixel (D col)
                const int hr = hp / 10, hc = hp - hr * 10;
                const int gr = ty + hr - 1, gc = tx + hc - 1;
                const bool vout = (hp < 100) && gr >= 0 && gr < HH && gc >= 0 && gc < WW;
                const int key = (gc & 7) << 4;         // consistent any-key for zeros

                f32x4 acc = {0.f, 0.f, 0.f, 0.f};
                #pragma unroll
                for (int kk = 0; kk < 3; ++kk) {
                    const short8 hb = *(const short8*)(sH + hp * 104 + kk * 32 + lq * 8);
                    acc = __builtin_amdgcn_mfma_f32_16x16x32_bf16(wa[kk], hb, acc, 0, 0, 0);
                }
                if (hp < 100) {                        // FIX: no OOB pad stores
                    uint2 u;
                    if (vout) {
                        u.x = (unsigned)f2bf(acc[0] + bv.x) | ((unsigned)f2bf(acc[1] + bv.y) << 16);
                        u.y = (unsigned)f2bf(acc[2] + bv.z) | ((unsigned)f2bf(acc[3] + bv.w) << 16);
                    } else { u.x = 0u; u.y = 0u; }
                    const int boff = hp * 384 + (ct * 16 + lq * 4) * 2;   // byte off
                    *(uint2*)((char*)sX1 + (boff ^ key)) = u;
                }
            }
        }
    }
    __syncthreads();

    // ========== Phase 3: conv main loop (byte-identical to r22) ===========
    const ushort_t* bbase = g_Wt + (size_t)(w * 48 + lm) * 192 + lq * 8;
    auto loadB9 = [&](short8 (&buf)[9], int tap, int half) {
        const ushort_t* p = bbase + tap * 18432 + half * 96;
        #pragma unroll
        for (int n = 0; n < 3; ++n)
            #pragma unroll
            for (int k2 = 0; k2 < 3; ++k2)
                buf[n * 3 + k2] = *(const short8*)(p + n * 3072 + k2 * 32);
    };

    int pr[4], pc[4];
    #pragma unroll
    for (int i = 0; i < 4; ++i) {
        const int px = i * 16 + lm;
        pr[i] = px >> 3; pc[i] = px & 7;
    }

    f32x4 acc[4][3];
    const f32x4 zf = {0.f, 0.f, 0.f, 0.f};
    #pragma unroll
    for (int i = 0; i < 4; ++i)
        #pragma unroll
        for (int n = 0; n < 3; ++n) acc[i][n] = zf;

    short8 bL[9], bH[9];
    loadB9(bL, 0, 0);

    #pragma unroll 1
    for (int tap = 0; tap < 9; ++tap) {
        const int ky = tap / 3, kx = tap - (tap / 3) * 3;
        int abyte[4], akey[4];
        #pragma unroll
        for (int i = 0; i < 4; ++i) {
            abyte[i] = ((pr[i] + ky) * 10 + pc[i] + kx) * 384;
            akey[i] = ((tx + pc[i] + kx - 1) & 7) << 4;
        }

        loadB9(bH, tap, 1);
        #pragma unroll
        for (int k2 = 0; k2 < 3; ++k2) {
            const int kk = k2;
            short8 a[4];
            #pragma unroll
            for (int i = 0; i < 4; ++i) {
                const int s = (kk * 64 + lq * 16) ^ akey[i];
                a[i] = *(const short8*)((const char*)sX1 + abyte[i] + s);
            }
            #pragma unroll
            for (int i = 0; i < 4; ++i)
                #pragma unroll
                for (int n = 0; n < 3; ++n)
                    acc[i][n] = __builtin_amdgcn_mfma_f32_16x16x32_bf16(
                        a[i], bL[n * 3 + k2], acc[i][n], 0, 0, 0);
        }

        if (tap < 8) loadB9(bL, tap + 1, 0);
        #pragma unroll
        for (int k2 = 0; k2 < 3; ++k2) {
            const int kk = 3 + k2;
            short8 a[4];
            #pragma unroll
            for (int i = 0; i < 4; ++i) {
                const int s = (kk * 64 + lq * 16) ^ akey[i];
                a[i] = *(const short8*)((const char*)sX1 + abyte[i] + s);
            }
            #pragma unroll
            for (int i = 0; i < 4; ++i)
                #pragma unroll
                for (int n = 0; n < 3; ++n)
                    acc[i][n] = __builtin_amdgcn_mfma_f32_16x16x32_bf16(
                        a[i], bH[n * 3 + k2], acc[i][n], 0, 0, 0);
        }
    }
    __syncthreads();                     // both waves done reading sX1

    // ===== Epilogue: silu via LDS transpose (sX1 dead), coalesced stores ==
    float* sY = (float*)sX1;             // 64 px * 100 dw = 25,600 B
    float bvn[3];
    #pragma unroll
    for (int n = 0; n < 3; ++n) bvn[n] = conv_b[w * 48 + n * 16 + lm];

    #pragma unroll
    for (int i = 0; i < 4; ++i)
        #pragma unroll
        for (int n = 0; n < 3; ++n)
            #pragma unroll
            for (int r4 = 0; r4 < 4; ++r4) {
                const float y = acc[i][n][r4] + bvn[n];
                const float sig = 1.f / (1.f + __expf(-y));
                sY[(i * 16 + lq * 4 + r4) * 100 + w * 48 + n * 16 + lm] = y * sig;
            }
    __syncthreads();

    #pragma unroll
    for (int c = 0; c < 12; ++c) {
        const int d = c * 512 + t * 4;                 // < 6144
        const int px = d / 96, b = d - px * 96;
        const int grow = ty + (px >> 3), gcol = tx + (px & 7);
        const size_t gdw = imgbase96 + (size_t)(grow * 56 + gcol) * 96 + b;
        const f32x4 yv = *(const f32x4*)(sY + px * 100 + b);
        const float4 xv = *(const float4*)(X + gdw);
        float4 o;
        o.x = xv.x + yv[0]; o.y = xv.y + yv[1];
        o.z = xv.z + yv[2]; o.w = xv.w + yv[3];
        *(float4*)(OUT + gdw) = o;
    }
}

extern "C" void kernel_launch(void* const* d_in, const int* in_sizes, int n_in,
                              void* d_out, int out_size, void* d_ws, size_t ws_size,
                              hipStream_t stream) {
    (void)in_sizes; (void)n_in; (void)out_size; (void)d_ws; (void)ws_size;
    const float* X    = (const float*)d_in[0];
    const float* ln_w = (const float*)d_in[1];
    const float* ln_b = (const float*)d_in[2];
    const float* Wi   = (const float*)d_in[3];
    const float* b_in = (const float*)d_in[4];
    const float* Wc   = (const float*)d_in[5];
    const float* cb   = (const float*)d_in[6];
    float* OUT = (float*)d_out;

    k0_wt<<<(9 * 96 * 192 + 255) / 256, 256, 0, stream>>>(Wc, Wi);
    k_fused<<<K2_NWG, 128, 0, stream>>>(X, ln_w, ln_b, b_in, cb, OUT);
}

// Round 26
// 130.724 us; speedup vs baseline: 1.3621x; 1.0940x over previous
//
#include <hip/hip_runtime.h>
#include <hip/hip_bf16.h>

#define D_MODEL 96
#define D_INNER 192
#define BATCH 32
#define HH 56
#define WW 56
#define NPIX (BATCH*HH*WW)   // 100352
#define LN_EPS 1e-5f
#define TAPS 18432           // shorts per tap slab (96 oc * 192 ic)
#define TAPBYTES 36864
#define K2_NWG 1568          // NPIX / 64 = 8 * 196 (bijective XCD swizzle)
#define K2_CPX 196

typedef unsigned short ushort_t;
typedef __attribute__((ext_vector_type(8))) short short8;   // 8 bf16 (4 VGPRs)
typedef __attribute__((ext_vector_type(4))) float f32x4;

// g_Wt: conv weights [tap][oc][ic] bf16, PRE-SWIZZLED within each slab by
// byte ^= ((byte/384 &7)<<4) (r17-verified). g_Wit: in_proj [oc][ic] bf16.
__device__ __align__(16) ushort_t g_Wt[9 * 96 * 192];
__device__ __align__(16) ushort_t g_Wit[192 * 96];

static __device__ __forceinline__ unsigned short f2bf(float f) {
    unsigned u = __float_as_uint(f);
    unsigned r = (u + 0x7fffu + ((u >> 16) & 1u)) >> 16;
    return (unsigned short)r;
}

// ---------------------------------------------------------------------------
// Kernel 0: weight prep (byte-identical to r17/r21, verified).
// ---------------------------------------------------------------------------
__global__ __launch_bounds__(256) void k0_wt(const float* __restrict__ Wc,
                                             const float* __restrict__ Wi) {
    const int o = blockIdx.x * 256 + threadIdx.x;
    if (o < 9 * 18432) {
        const int tap = o / 18432;
        const int s = o - tap * 18432;
        const int sl = s ^ (((s / 192) & 7) << 3);   // logical short index
        const int oc = sl / 192, ic = sl - oc * 192;
        g_Wt[o] = f2bf(Wc[(tap * 192 + ic) * 96 + oc]);
    }
    if (o < 192 * 96) {
        const int oc = o / 96, ic = o - oc * 96;
        g_Wit[o] = f2bf(Wi[ic * 384 + oc]);
    }
}

// ---------------------------------------------------------------------------
// Kernel 1: LayerNorm + in_projection (r21-verified): X1 stores pre-swizzled
// per pixel (byte ^= ((pix&7)<<4); 56 % 8 == 0 -> key reconstructible in k2).
// ---------------------------------------------------------------------------
__global__ __launch_bounds__(256) void k1_ln_proj(
    const float* __restrict__ X, const float* __restrict__ ln_w,
    const float* __restrict__ ln_b, const float* __restrict__ b_in,
    ushort_t* __restrict__ X1)
{
    __shared__ ushort_t sH[64 * 104];
    __shared__ ushort_t sO[64 * 200];
    const int t = threadIdx.x;

    const int g = t >> 2, tig = t & 3;
    const int pix = blockIdx.x * 64 + g;
    const float* xp = X + (size_t)pix * 96 + tig * 24;
    float4 xq[6];
    float s = 0.f;
    #pragma unroll
    for (int c = 0; c < 6; ++c) {
        xq[c] = *(const float4*)(xp + c * 4);
        s += xq[c].x + xq[c].y + xq[c].z + xq[c].w;
    }
    s += __shfl_xor(s, 1, 4);
    s += __shfl_xor(s, 2, 4);
    const float mu = s * (1.f / 96.f);
    float v = 0.f;
    #pragma unroll
    for (int c = 0; c < 6; ++c) {
        const float d0 = xq[c].x - mu, d1 = xq[c].y - mu;
        const float d2 = xq[c].z - mu, d3 = xq[c].w - mu;
        v += d0 * d0 + d1 * d1 + d2 * d2 + d3 * d3;
    }
    v += __shfl_xor(v, 1, 4);
    v += __shfl_xor(v, 2, 4);
    const float rs = rsqrtf(v * (1.f / 96.f) + LN_EPS);
    #pragma unroll
    for (int c = 0; c < 6; ++c) {
        const float4 lw = *(const float4*)(ln_w + tig * 24 + c * 4);
        const float4 lb = *(const float4*)(ln_b + tig * 24 + c * 4);
        const unsigned p0 = (unsigned)f2bf((xq[c].x - mu) * rs * lw.x + lb.x)
                          | ((unsigned)f2bf((xq[c].y - mu) * rs * lw.y + lb.y) << 16);
        const unsigned p1 = (unsigned)f2bf((xq[c].z - mu) * rs * lw.z + lb.z)
                          | ((unsigned)f2bf((xq[c].w - mu) * rs * lw.w + lb.w) << 16);
        uint2 u; u.x = p0; u.y = p1;
        *(uint2*)&sH[g * 104 + tig * 24 + c * 4] = u;
    }
    __syncthreads();

    const int w = t >> 6, l = t & 63;
    const int lm = l & 15, lq = l >> 4;
    const ushort_t* hp = &sH[(w * 16 + lm) * 104 + lq * 8];

    f32x4 acc[12];
    const f32x4 zf = {0.f, 0.f, 0.f, 0.f};
    #pragma unroll
    for (int mt = 0; mt < 12; ++mt) acc[mt] = zf;

    #pragma unroll
    for (int kk = 0; kk < 3; ++kk) {
        const short8 hb = *(const short8*)(hp + kk * 32);
        #pragma unroll
        for (int mt = 0; mt < 12; ++mt) {
            const short8 wa = *(const short8*)(g_Wit + (mt * 16 + lm) * 96 + kk * 32 + lq * 8);
            acc[mt] = __builtin_amdgcn_mfma_f32_16x16x32_bf16(wa, hb, acc[mt], 0, 0, 0);
        }
    }

    #pragma unroll
    for (int mt = 0; mt < 12; ++mt) {
        const int oc0 = mt * 16 + lq * 4;
        const float4 bv = *(const float4*)(b_in + oc0);
        uint2 u;
        u.x = (unsigned)f2bf(acc[mt][0] + bv.x) | ((unsigned)f2bf(acc[mt][1] + bv.y) << 16);
        u.y = (unsigned)f2bf(acc[mt][2] + bv.z) | ((unsigned)f2bf(acc[mt][3] + bv.w) << 16);
        *(uint2*)&sO[(w * 16 + lm) * 200 + oc0] = u;
    }
    __syncthreads();

    const char* sOb = (const char*)sO + w * 16 * 400;
    char* gdst = (char*)X1 + (size_t)(blockIdx.x * 64 + w * 16) * 384;
    #pragma unroll
    for (int c = 0; c < 6; ++c) {
        const int gb = c * 1024 + l * 16;
        const int px = gb / 384, b = gb - px * 384;
        const uint4 val = *(const uint4*)(sOb + px * 400 + b);
        // pre-swizzled store: bits 4-6 of the in-block offset XOR'd by px&7
        *(uint4*)(gdst + (gb ^ ((px & 7) << 4))) = val;
    }
}

// ---------------------------------------------------------------------------
// Kernel 2: 3x3 conv (192 -> 96) MFMA + bias + SiLU + residual.
// r21-verified (best measured k2 = 98.4 us; FETCH 42 MB, WRITE 37.6 MB,
// conflicts 150 K): halo 10x10x192 bf16 staged verbatim (X1 pre-swizzled ->
// A-reads XOR per-pixel key, bank-conflict-free); weights via pre-swizzled
// g_Wt + linear global_load_lds single slab. Main loop: zero global gathers.
// ---------------------------------------------------------------------------
__global__ __launch_bounds__(128) void k2_conv_mfma(
    const ushort_t* __restrict__ X1, const float* __restrict__ conv_b,
    const float* __restrict__ X, float* __restrict__ OUT)
{
    __shared__ ushort_t sX[100 * 192];   // 38,400 B halo (pre-swizzled blocks)
    __shared__ ushort_t sWs[TAPS];       // 36,864 B tap slab (pre-swizzled)
    const int t = threadIdx.x;
    const int w = t >> 6, l = t & 63;
    const int lm = l & 15, lq = l >> 4;

    const int lb = ((int)blockIdx.x & 7) * K2_CPX + ((int)blockIdx.x >> 3);
    const int img = lb / 49, tile = lb - img * 49;
    const int ty = (tile / 7) * 8, tx = (tile % 7) * 8;
    const size_t imgbase = (size_t)img * 3136 * 192;

    // ---- stage halo: verbatim copies (swizzle travels with the data) ----
    for (int idx = t; idx < 2400; idx += 128) {       // 100 px * 24 uint4
        const int hp2 = idx / 24, q = idx - hp2 * 24;
        const int hr = hp2 / 10, hc = hp2 - hr * 10;
        const int gr = ty + hr - 1, gc = tx + hc - 1;
        uint4 val = make_uint4(0u, 0u, 0u, 0u);
        if (gr >= 0 && gr < HH && gc >= 0 && gc < WW)
            val = *(const uint4*)(X1 + imgbase + (size_t)(gr * WW + gc) * 192 + q * 8);
        *(uint4*)&sX[hp2 * 192 + q * 8] = val;
    }

    // ---- W staging: linear async copy (src and dest both linear) ----
    auto stageW = [&](int tap) {
        const char* g = (const char*)g_Wt + (size_t)tap * TAPBYTES + t * 16;
        char* d = (char*)sWs + t * 16;
        #pragma unroll
        for (int j = 0; j < 18; ++j)
            __builtin_amdgcn_global_load_lds(
                (const __attribute__((address_space(1))) unsigned*)(g + j * 2048),
                (__attribute__((address_space(3))) unsigned*)(d + j * 2048),
                16, 0, 0);
    };
    stageW(0);
    __syncthreads();   // halo written + tap-0 slab drained

    int pr[4], pc[4];
    #pragma unroll
    for (int i = 0; i < 4; ++i) {
        const int px = i * 16 + lm;
        pr[i] = px >> 3; pc[i] = px & 7;
    }

    f32x4 acc[4][3];
    const f32x4 zf = {0.f, 0.f, 0.f, 0.f};
    #pragma unroll
    for (int i = 0; i < 4; ++i)
        #pragma unroll
        for (int n = 0; n < 3; ++n) acc[i][n] = zf;

    const int bkey = (lm & 7) << 4;
    const int brow0 = (w * 48 + lm) * 384 + lq * 16;   // wave's oc base row

    #pragma unroll 1
    for (int tap = 0; tap < 9; ++tap) {
        const int ky = tap / 3, kx = tap - (tap / 3) * 3;
        int abyte[4], akey[4];
        #pragma unroll
        for (int i = 0; i < 4; ++i) {
            abyte[i] = ((pr[i] + ky) * 10 + pc[i] + kx) * 384;
            akey[i] = ((tx + pc[i] + kx - 1) & 7) << 4;   // zeros if border
        }

        #pragma unroll
        for (int kk = 0; kk < 6; ++kk) {
            short8 b[3];
            #pragma unroll
            for (int n = 0; n < 3; ++n) {
                const int A = brow0 + n * 6144 + kk * 64;
                b[n] = *(const short8*)((const char*)sWs + (A ^ bkey));
            }
            short8 a[4];
            #pragma unroll
            for (int i = 0; i < 4; ++i) {
                const int s = (kk * 64 + lq * 16) ^ akey[i];
                a[i] = *(const short8*)((const char*)sX + abyte[i] + s);
            }
            #pragma unroll
            for (int i = 0; i < 4; ++i)
                #pragma unroll
                for (int n = 0; n < 3; ++n)
                    acc[i][n] = __builtin_amdgcn_mfma_f32_16x16x32_bf16(
                        a[i], b[n], acc[i][n], 0, 0, 0);
        }
        __syncthreads();                 // all waves done reading sWs (+sX last tap)
        if (tap < 8) { stageW(tap + 1); __syncthreads(); }
    }

    // ---- epilogue: silu via LDS transpose (sX dead), coalesced stores ----
    float* sY = (float*)sX;              // 64 px * 100 dw = 25,600 B
    float bvn[3];
    #pragma unroll
    for (int n = 0; n < 3; ++n) bvn[n] = conv_b[w * 48 + n * 16 + lm];

    #pragma unroll
    for (int i = 0; i < 4; ++i)
        #pragma unroll
        for (int n = 0; n < 3; ++n)
            #pragma unroll
            for (int r4 = 0; r4 < 4; ++r4) {
                const float y = acc[i][n][r4] + bvn[n];
                const float sig = 1.f / (1.f + __expf(-y));
                sY[(i * 16 + lq * 4 + r4) * 100 + w * 48 + n * 16 + lm] = y * sig;
            }
    __syncthreads();

    #pragma unroll
    for (int c = 0; c < 12; ++c) {
        const int d = c * 512 + t * 4;                 // < 6144
        const int px = d / 96, b = d - px * 96;
        const int grow = ty + (px >> 3), gcol = tx + (px & 7);
        const size_t gdw = ((size_t)img * 3136 + grow * 56 + gcol) * 96 + b;
        const f32x4 yv = *(const f32x4*)(sY + px * 100 + b);
        const float4 xv = *(const float4*)(X + gdw);
        float4 o;
        o.x = xv.x + yv[0]; o.y = xv.y + yv[1];
        o.z = xv.z + yv[2]; o.w = xv.w + yv[3];
        *(float4*)(OUT + gdw) = o;
    }
}

extern "C" void kernel_launch(void* const* d_in, const int* in_sizes, int n_in,
                              void* d_out, int out_size, void* d_ws, size_t ws_size,
                              hipStream_t stream) {
    (void)in_sizes; (void)n_in; (void)out_size; (void)ws_size;
    const float* X    = (const float*)d_in[0];
    const float* ln_w = (const float*)d_in[1];
    const float* ln_b = (const float*)d_in[2];
    const float* Wi   = (const float*)d_in[3];
    const float* b_in = (const float*)d_in[4];
    const float* Wc   = (const float*)d_in[5];
    const float* cb   = (const float*)d_in[6];
    float* OUT = (float*)d_out;
    ushort_t* X1 = (ushort_t*)d_ws;   // 100352*192 bf16 = 38.5 MB (pre-swizzled)

    k0_wt<<<(9 * 96 * 192 + 255) / 256, 256, 0, stream>>>(Wc, Wi);
    k1_ln_proj<<<NPIX / 64, 256, 0, stream>>>(X, ln_w, ln_b, b_in, X1);
    k2_conv_mfma<<<K2_NWG, 128, 0, stream>>>(X1, cb, X, OUT);
}

// Round 27
// 97.094 us; speedup vs baseline: 1.8339x; 1.3464x over previous
//
#include <hip/hip_runtime.h>
#include <hip/hip_bf16.h>

#define D_MODEL 96
#define D_INNER 192
#define BATCH 32
#define HH 56
#define WW 56
#define NPIX (BATCH*HH*WW)   // 100352
#define LN_EPS 1e-5f
#define WSLAB 12288          // shorts per combined tap slab (96 oc * 128 pad)
#define WSLABB 24576         // bytes
#define K2_NWG 1568          // NPIX / 64 = 8 * 196 (bijective XCD swizzle)
#define K2_CPX 196

typedef unsigned short ushort_t;
typedef __attribute__((ext_vector_type(8))) short short8;   // 8 bf16 (4 VGPRs)
typedef __attribute__((ext_vector_type(4))) float f32x4;

// g_Wcomb[tap][oc][s]: COMBINED weights (Wi_live @ Wc[tap]), bf16, rows
// padded to 128 shorts (256 B, 128-aligned) and PRE-SWIZZLED within each row
// by short-index XOR ((oc&7)<<3) (= byte XOR ((oc&7)<<4)); logical ic<96.
// g_Bt[tap][oc] = b_in_live @ Wc[tap] (fp32); g_Ball = conv_b + sum_tap Bt.
__device__ __align__(16) ushort_t g_Wcomb[9 * WSLAB];
__device__ float g_Bt[9 * 96];
__device__ float g_Ball[96];

static __device__ __forceinline__ unsigned short f2bf(float f) {
    unsigned u = __float_as_uint(f);
    unsigned r = (u + 0x7fffu + ((u >> 16) & 1u)) >> 16;
    return (unsigned short)r;
}

// ---------------------------------------------------------------------------
// Kernel 0: fold proj into conv.  Wcomb[tap][oc][c] = sum_j Wi[c*384+j] *
// Wc[(tap*192+j)*96+oc]  (c = LN-output channel, j = x1 channel < 192).
// Stored padded+pre-swizzled so k2 can linear-copy and XOR-read.
// ---------------------------------------------------------------------------
__global__ __launch_bounds__(256) void k0_wt(const float* __restrict__ Wc,
                                             const float* __restrict__ Wi,
                                             const float* __restrict__ b_in,
                                             const float* __restrict__ conv_b) {
    const int o = blockIdx.x * 256 + threadIdx.x;
    if (o < 9 * WSLAB) {
        const int tap = o / WSLAB;
        const int rem = o - tap * WSLAB;
        const int oc = rem >> 7, s = rem & 127;
        const int sl = s ^ ((oc & 7) << 3);          // logical c index
        float acc = 0.f;
        if (sl < 96) {
            const float* wi = Wi + sl * 384;
            const float* wc = Wc + (size_t)tap * 192 * 96 + oc;
            #pragma unroll 4
            for (int j = 0; j < 192; ++j) acc += wi[j] * wc[j * 96];
        }
        g_Wcomb[o] = f2bf(acc);
    } else if (o < 9 * WSLAB + 864) {
        const int idx = o - 9 * WSLAB;
        const int tap = idx / 96, oc = idx - tap * 96;
        float acc = 0.f;
        const float* wc = Wc + (size_t)tap * 192 * 96 + oc;
        for (int j = 0; j < 192; ++j) acc += b_in[j] * wc[j * 96];
        g_Bt[idx] = acc;
    } else if (o < 9 * WSLAB + 960) {
        const int oc = o - 9 * WSLAB - 864;
        float acc = conv_b[oc];
        for (int tap = 0; tap < 9; ++tap) {
            const float* wc = Wc + (size_t)tap * 192 * 96 + oc;
            for (int j = 0; j < 192; ++j) acc += b_in[j] * wc[j * 96];
        }
        g_Ball[oc] = acc;
    }
}

// ---------------------------------------------------------------------------
// Kernel 1: LayerNorm ONLY (proj is folded into k2's weights).
// 256 thr, 64 px/block; 4 threads per pixel own 24 consecutive channels;
// h written bf16 dense (96 sh/px) with 3 coalesced uint4 stores per thread.
// ---------------------------------------------------------------------------
__global__ __launch_bounds__(256) void k1_ln(
    const float* __restrict__ X, const float* __restrict__ ln_w,
    const float* __restrict__ ln_b, ushort_t* __restrict__ H)
{
    const int t = threadIdx.x;
    const int g = t >> 2, tig = t & 3;
    const int pix = blockIdx.x * 64 + g;
    const float* xp = X + (size_t)pix * 96 + tig * 24;
    float4 xq[6];
    float s = 0.f;
    #pragma unroll
    for (int c = 0; c < 6; ++c) {
        xq[c] = *(const float4*)(xp + c * 4);
        s += xq[c].x + xq[c].y + xq[c].z + xq[c].w;
    }
    s += __shfl_xor(s, 1, 4);
    s += __shfl_xor(s, 2, 4);
    const float mu = s * (1.f / 96.f);
    float v = 0.f;
    #pragma unroll
    for (int c = 0; c < 6; ++c) {
        const float d0 = xq[c].x - mu, d1 = xq[c].y - mu;
        const float d2 = xq[c].z - mu, d3 = xq[c].w - mu;
        v += d0 * d0 + d1 * d1 + d2 * d2 + d3 * d3;
    }
    v += __shfl_xor(v, 1, 4);
    v += __shfl_xor(v, 2, 4);
    const float rs = rsqrtf(v * (1.f / 96.f) + LN_EPS);
    unsigned u[12];
    #pragma unroll
    for (int c = 0; c < 6; ++c) {
        const float4 lw = *(const float4*)(ln_w + tig * 24 + c * 4);
        const float4 lb = *(const float4*)(ln_b + tig * 24 + c * 4);
        u[c * 2 + 0] = (unsigned)f2bf((xq[c].x - mu) * rs * lw.x + lb.x)
                     | ((unsigned)f2bf((xq[c].y - mu) * rs * lw.y + lb.y) << 16);
        u[c * 2 + 1] = (unsigned)f2bf((xq[c].z - mu) * rs * lw.z + lb.z)
                     | ((unsigned)f2bf((xq[c].w - mu) * rs * lw.w + lb.w) << 16);
    }
    ushort_t* hp = H + (size_t)pix * 96 + tig * 24;
    *(uint4*)(hp + 0)  = make_uint4(u[0], u[1], u[2], u[3]);
    *(uint4*)(hp + 8)  = make_uint4(u[4], u[5], u[6], u[7]);
    *(uint4*)(hp + 16) = make_uint4(u[8], u[9], u[10], u[11]);
}

// ---------------------------------------------------------------------------
// Kernel 2: folded conv (h, 96ch, K=864) + bias + SiLU + residual.
// r21 structure with HALF the work: halo = 10x10x96 bf16, rows padded to
// 256 B + XOR-swizzled on the ds_write side (key=(hp&7)<<4, reconstructed
// at read); weight slab = pre-swizzled g_Wcomb via linear global_load_lds.
// Wave = 64 px x 48 oc; 3 kk-steps/tap, 36 MFMA/tap. LDS 50,176 B ->
// 3 blocks/CU. Border bias correction (exact b_in handling) in epilogue.
// ---------------------------------------------------------------------------
__global__ __launch_bounds__(128) void k2_conv_mfma(
    const ushort_t* __restrict__ H, const float* __restrict__ X,
    float* __restrict__ OUT)
{
    __shared__ ushort_t sH[100 * 128];   // 25,600 B halo (swizzled 256-B rows)
    __shared__ ushort_t sWs[WSLAB];      // 24,576 B tap slab (pre-swizzled)
    const int t = threadIdx.x;
    const int w = t >> 6, l = t & 63;
    const int lm = l & 15, lq = l >> 4;

    const int lb = ((int)blockIdx.x & 7) * K2_CPX + ((int)blockIdx.x >> 3);
    const int img = lb / 49, tile = lb - img * 49;
    const int ty = (tile / 7) * 8, tx = (tile % 7) * 8;
    const size_t imgbase = (size_t)img * 3136;

    // ---- stage halo h: dense global -> swizzled 256-B LDS rows ----
    for (int idx = t; idx < 1200; idx += 128) {       // 100 px * 12 uint4
        const int px = idx / 12, c = idx - px * 12;
        const int hr = px / 10, hc = px - hr * 10;
        const int gr = ty + hr - 1, gc = tx + hc - 1;
        uint4 val = make_uint4(0u, 0u, 0u, 0u);
        if (gr >= 0 && gr < HH && gc >= 0 && gc < WW)
            val = *(const uint4*)(H + (imgbase + gr * WW + gc) * 96 + c * 8);
        *(uint4*)((char*)sH + px * 256 + ((c * 16) ^ ((px & 7) << 4))) = val;
    }

    // ---- W staging: linear async copy (src and dest both linear) ----
    auto stageW = [&](int tap) {
        const char* g = (const char*)g_Wcomb + (size_t)tap * WSLABB + t * 16;
        char* d = (char*)sWs + t * 16;
        #pragma unroll
        for (int j = 0; j < 12; ++j)
            __builtin_amdgcn_global_load_lds(
                (const __attribute__((address_space(1))) unsigned*)(g + j * 2048),
                (__attribute__((address_space(3))) unsigned*)(d + j * 2048),
                16, 0, 0);
    };
    stageW(0);
    __syncthreads();   // halo written + tap-0 slab drained

    int pr[4], pc[4];
    #pragma unroll
    for (int i = 0; i < 4; ++i) {
        const int px = i * 16 + lm;
        pr[i] = px >> 3; pc[i] = px & 7;
    }

    f32x4 acc[4][3];
    const f32x4 zf = {0.f, 0.f, 0.f, 0.f};
    #pragma unroll
    for (int i = 0; i < 4; ++i)
        #pragma unroll
        for (int n = 0; n < 3; ++n) acc[i][n] = zf;

    const int bkey = (lm & 7) << 4;
    const int brow0 = (w * 48 + lm) * 256 + lq * 16;   // wave's oc base row

    #pragma unroll 1
    for (int tap = 0; tap < 9; ++tap) {
        const int ky = tap / 3, kx = tap - (tap / 3) * 3;
        int abyte[4], akey[4];
        #pragma unroll
        for (int i = 0; i < 4; ++i) {
            const int hp = (pr[i] + ky) * 10 + pc[i] + kx;
            abyte[i] = hp * 256;
            akey[i] = (hp & 7) << 4;
        }

        #pragma unroll
        for (int kk = 0; kk < 3; ++kk) {
            short8 b[3];
            #pragma unroll
            for (int n = 0; n < 3; ++n) {
                const int A = brow0 + n * 4096 + kk * 64;   // n*16 rows * 256 B
                b[n] = *(const short8*)((const char*)sWs + (A ^ bkey));
            }
            short8 a[4];
            #pragma unroll
            for (int i = 0; i < 4; ++i) {
                const int s = (kk * 64 + lq * 16) ^ akey[i];
                a[i] = *(const short8*)((const char*)sH + abyte[i] + s);
            }
            #pragma unroll
            for (int i = 0; i < 4; ++i)
                #pragma unroll
                for (int n = 0; n < 3; ++n)
                    acc[i][n] = __builtin_amdgcn_mfma_f32_16x16x32_bf16(
                        a[i], b[n], acc[i][n], 0, 0, 0);
        }
        __syncthreads();                 // all waves done reading sWs (+sH last tap)
        if (tap < 8) { stageW(tap + 1); __syncthreads(); }
    }

    // ---- epilogue: bias (exact, border-corrected) + silu + residual ----
    float* sY = (float*)sH;              // 64 px * 100 dw = 25,600 B (sH dead)
    float bvn[3];
    #pragma unroll
    for (int n = 0; n < 3; ++n) bvn[n] = g_Ball[w * 48 + n * 16 + lm];

    const bool borderTile = (ty == 0) || (ty == 48) || (tx == 0) || (tx == 48);
    float bt[3][9];
    if (borderTile) {
        #pragma unroll
        for (int n = 0; n < 3; ++n)
            #pragma unroll
            for (int d2 = 0; d2 < 9; ++d2)
                bt[n][d2] = g_Bt[d2 * 96 + w * 48 + n * 16 + lm];
    }

    #pragma unroll
    for (int i = 0; i < 4; ++i)
        #pragma unroll
        for (int r4 = 0; r4 < 4; ++r4) {
            const int p = i * 16 + lq * 4 + r4;
            const int grow = ty + (p >> 3), gcol = tx + (p & 7);
            float corr[3] = {0.f, 0.f, 0.f};
            if (borderTile) {
                #pragma unroll
                for (int dy = 0; dy < 3; ++dy)
                    #pragma unroll
                    for (int dx = 0; dx < 3; ++dx) {
                        const int gr2 = grow + dy - 1, gc2 = gcol + dx - 1;
                        if (gr2 < 0 || gr2 >= HH || gc2 < 0 || gc2 >= WW) {
                            corr[0] += bt[0][dy * 3 + dx];
                            corr[1] += bt[1][dy * 3 + dx];
                            corr[2] += bt[2][dy * 3 + dx];
                        }
                    }
            }
            #pragma unroll
            for (int n = 0; n < 3; ++n) {
                const float y = acc[i][n][r4] + bvn[n] - corr[n];
                const float sig = 1.f / (1.f + __expf(-y));
                sY[p * 100 + w * 48 + n * 16 + lm] = y * sig;
            }
        }
    __syncthreads();

    #pragma unroll
    for (int c = 0; c < 12; ++c) {
        const int d = c * 512 + t * 4;                 // < 6144
        const int px = d / 96, b = d - px * 96;
        const int grow = ty + (px >> 3), gcol = tx + (px & 7);
        const size_t gdw = (imgbase + grow * WW + gcol) * 96 + b;
        const f32x4 yv = *(const f32x4*)(sY + px * 100 + b);
        const float4 xv = *(const float4*)(X + gdw);
        float4 o;
        o.x = xv.x + yv[0]; o.y = xv.y + yv[1];
        o.z = xv.z + yv[2]; o.w = xv.w + yv[3];
        *(float4*)(OUT + gdw) = o;
    }
}

extern "C" void kernel_launch(void* const* d_in, const int* in_sizes, int n_in,
                              void* d_out, int out_size, void* d_ws, size_t ws_size,
                              hipStream_t stream) {
    (void)in_sizes; (void)n_in; (void)out_size; (void)ws_size;
    const float* X    = (const float*)d_in[0];
    const float* ln_w = (const float*)d_in[1];
    const float* ln_b = (const float*)d_in[2];
    const float* Wi   = (const float*)d_in[3];
    const float* b_in = (const float*)d_in[4];
    const float* Wc   = (const float*)d_in[5];
    const float* cb   = (const float*)d_in[6];
    float* OUT = (float*)d_out;
    ushort_t* H = (ushort_t*)d_ws;   // 100352*96 bf16 = 19.3 MB (LN output)

    k0_wt<<<(9 * WSLAB + 960 + 255) / 256, 256, 0, stream>>>(Wc, Wi, b_in, cb);
    k1_ln<<<NPIX / 64, 256, 0, stream>>>(X, ln_w, ln_b, H);
    k2_conv_mfma<<<K2_NWG, 128, 0, stream>>>(H, X, OUT);
}

// Round 28
// 92.835 us; speedup vs baseline: 1.9180x; 1.0459x over previous
//
#include <hip/hip_runtime.h>
#include <hip/hip_bf16.h>

#define D_MODEL 96
#define D_INNER 192
#define BATCH 32
#define HH 56
#define WW 56
#define NPIX (BATCH*HH*WW)   // 100352
#define LN_EPS 1e-5f
#define WSLAB 12288          // shorts per combined tap slab (96 oc * 128 pad)
#define WSLABB 24576         // bytes
#define K2_NWG 1568          // NPIX / 64 = 8 * 196 (bijective XCD swizzle)
#define K2_CPX 196

typedef unsigned short ushort_t;
typedef __attribute__((ext_vector_type(8))) short short8;   // 8 bf16 (4 VGPRs)
typedef __attribute__((ext_vector_type(4))) float f32x4;

// g_Wcomb[tap][oc][s]: combined (Wi_live @ Wc[tap]) bf16, 256-B rows,
// pre-swizzled by short-index XOR ((oc&7)<<3) (r27-verified).
// g_Bt[tap][oc] = b_in @ Wc[tap]; g_Ball = conv_b + sum_tap Bt.
__device__ __align__(16) ushort_t g_Wcomb[9 * WSLAB];
__device__ float g_Bt[9 * 96];
__device__ float g_Ball[96];

static __device__ __forceinline__ unsigned short f2bf(float f) {
    unsigned u = __float_as_uint(f);
    unsigned r = (u + 0x7fffu + ((u >> 16) & 1u)) >> 16;
    return (unsigned short)r;
}

// ---------------------------------------------------------------------------
// Kernel 0: weight fold (r27-verified math). NEW: live Wi half staged into
// LDS (193-float padded rows, coalesced fill, conflict-free reads) — r27's
// fold loop read Wi lane-strided (64 lines/instr); this removes it.
// ---------------------------------------------------------------------------
__global__ __launch_bounds__(256) void k0_wt(const float* __restrict__ Wc,
                                             const float* __restrict__ Wi,
                                             const float* __restrict__ b_in,
                                             const float* __restrict__ conv_b) {
    __shared__ float sWi[96 * 193];   // 74,112 B
    const int t = threadIdx.x;
    for (int i = t; i < 96 * 192; i += 256) {
        const int c = i / 192, j = i - c * 192;
        sWi[c * 193 + j] = Wi[c * 384 + j];
    }
    __syncthreads();

    const int o = blockIdx.x * 256 + t;
    if (o < 9 * WSLAB) {
        const int tap = o / WSLAB;
        const int rem = o - tap * WSLAB;
        const int oc = rem >> 7, s = rem & 127;
        const int sl = s ^ ((oc & 7) << 3);          // logical c index
        float acc = 0.f;
        if (sl < 96) {
            const float* wi = sWi + sl * 193;
            const float* wc = Wc + (size_t)tap * 192 * 96 + oc;
            #pragma unroll 4
            for (int j = 0; j < 192; ++j) acc += wi[j] * wc[j * 96];
        }
        g_Wcomb[o] = f2bf(acc);
    } else if (o < 9 * WSLAB + 864) {
        const int idx = o - 9 * WSLAB;
        const int tap = idx / 96, oc = idx - tap * 96;
        float acc = 0.f;
        const float* wc = Wc + (size_t)tap * 192 * 96 + oc;
        for (int j = 0; j < 192; ++j) acc += b_in[j] * wc[j * 96];
        g_Bt[idx] = acc;
    } else if (o < 9 * WSLAB + 960) {
        const int oc = o - 9 * WSLAB - 864;
        float acc = conv_b[oc];
        for (int tap = 0; tap < 9; ++tap) {
            const float* wc = Wc + (size_t)tap * 192 * 96 + oc;
            for (int j = 0; j < 192; ++j) acc += b_in[j] * wc[j * 96];
        }
        g_Ball[oc] = acc;
    }
}

// ---------------------------------------------------------------------------
// FUSED kernel: LN (halo recompute) + folded conv + bias + SiLU + residual.
// Phase 1: LN for the 100 halo px, written bf16 DIRECTLY into swizzled
//   256-B sH rows (zeros for border px = folded-conv semantics; exact bias
//   via r27's verified g_Ball/g_Bt border correction). stageW(0) issued
//   before Phase 1 so the tap-0 weight copy rides under the LN compute.
// Phase 2: conv main loop + epilogue BYTE-IDENTICAL to r27's k2 (verified).
// Eliminates k1 (~12 us) and the 49 MB H round-trip.
// ---------------------------------------------------------------------------
__global__ __launch_bounds__(128) void k_fused(
    const float* __restrict__ X, const float* __restrict__ ln_w,
    const float* __restrict__ ln_b, float* __restrict__ OUT)
{
    __shared__ ushort_t sH[100 * 128];   // 25,600 B halo h (swizzled rows)
    __shared__ ushort_t sWs[WSLAB];      // 24,576 B tap slab (pre-swizzled)
    const int t = threadIdx.x;
    const int w = t >> 6, l = t & 63;
    const int lm = l & 15, lq = l >> 4;

    const int lb = ((int)blockIdx.x & 7) * K2_CPX + ((int)blockIdx.x >> 3);
    const int img = lb / 49, tile = lb - img * 49;
    const int ty = (tile / 7) * 8, tx = (tile % 7) * 8;
    const size_t imgbase = (size_t)img * 3136;

    // ---- W staging: linear async copy (r27-verified) ----
    auto stageW = [&](int tap) {
        const char* g = (const char*)g_Wcomb + (size_t)tap * WSLABB + t * 16;
        char* d = (char*)sWs + t * 16;
        #pragma unroll
        for (int j = 0; j < 12; ++j)
            __builtin_amdgcn_global_load_lds(
                (const __attribute__((address_space(1))) unsigned*)(g + j * 2048),
                (__attribute__((address_space(3))) unsigned*)(d + j * 2048),
                16, 0, 0);
    };
    stageW(0);                           // overlaps Phase-1 LN

    // ================= Phase 1: LN halo -> swizzled sH ====================
    {
        const int g4 = t >> 2, tig = t & 3;
        #pragma unroll 1
        for (int it = 0; it < 4; ++it) {
            const int px = it * 32 + g4;
            if (px >= 100) continue;
            const int hr = px / 10, hc = px - hr * 10;
            const int gr = ty + hr - 1, gc = tx + hc - 1;
            const bool valid = gr >= 0 && gr < HH && gc >= 0 && gc < WW;
            const float* xp = X + (imgbase + gr * WW + gc) * 96 + tig * 24;
            uint4 out[3];
            if (valid) {
                float4 xq[6];
                float s = 0.f;
                #pragma unroll
                for (int c = 0; c < 6; ++c) {
                    xq[c] = *(const float4*)(xp + c * 4);
                    s += xq[c].x + xq[c].y + xq[c].z + xq[c].w;
                }
                s += __shfl_xor(s, 1, 4);
                s += __shfl_xor(s, 2, 4);
                const float mu = s * (1.f / 96.f);
                float v = 0.f;
                #pragma unroll
                for (int c = 0; c < 6; ++c) {
                    const float d0 = xq[c].x - mu, d1 = xq[c].y - mu;
                    const float d2 = xq[c].z - mu, d3 = xq[c].w - mu;
                    v += d0 * d0 + d1 * d1 + d2 * d2 + d3 * d3;
                }
                v += __shfl_xor(v, 1, 4);
                v += __shfl_xor(v, 2, 4);
                const float rs = rsqrtf(v * (1.f / 96.f) + LN_EPS);
                unsigned u[12];
                #pragma unroll
                for (int c = 0; c < 6; ++c) {
                    const float4 lw = *(const float4*)(ln_w + tig * 24 + c * 4);
                    const float4 lb2 = *(const float4*)(ln_b + tig * 24 + c * 4);
                    u[c * 2 + 0] = (unsigned)f2bf((xq[c].x - mu) * rs * lw.x + lb2.x)
                                 | ((unsigned)f2bf((xq[c].y - mu) * rs * lw.y + lb2.y) << 16);
                    u[c * 2 + 1] = (unsigned)f2bf((xq[c].z - mu) * rs * lw.z + lb2.z)
                                 | ((unsigned)f2bf((xq[c].w - mu) * rs * lw.w + lb2.w) << 16);
                }
                out[0] = make_uint4(u[0], u[1], u[2], u[3]);
                out[1] = make_uint4(u[4], u[5], u[6], u[7]);
                out[2] = make_uint4(u[8], u[9], u[10], u[11]);
            } else {
                out[0] = out[1] = out[2] = make_uint4(0u, 0u, 0u, 0u);
            }
            const int key = (px & 7) << 4;
            char* rowp = (char*)sH + px * 256;
            #pragma unroll
            for (int q = 0; q < 3; ++q)
                *(uint4*)(rowp + (((tig * 3 + q) * 16) ^ key)) = out[q];
        }
    }
    __syncthreads();   // sH written + tap-0 slab drained (vmcnt)

    // ========== Phase 2: conv main loop (byte-identical to r27) ===========
    int pr[4], pc[4];
    #pragma unroll
    for (int i = 0; i < 4; ++i) {
        const int px = i * 16 + lm;
        pr[i] = px >> 3; pc[i] = px & 7;
    }

    f32x4 acc[4][3];
    const f32x4 zf = {0.f, 0.f, 0.f, 0.f};
    #pragma unroll
    for (int i = 0; i < 4; ++i)
        #pragma unroll
        for (int n = 0; n < 3; ++n) acc[i][n] = zf;

    const int bkey = (lm & 7) << 4;
    const int brow0 = (w * 48 + lm) * 256 + lq * 16;   // wave's oc base row

    #pragma unroll 1
    for (int tap = 0; tap < 9; ++tap) {
        const int ky = tap / 3, kx = tap - (tap / 3) * 3;
        int abyte[4], akey[4];
        #pragma unroll
        for (int i = 0; i < 4; ++i) {
            const int hp = (pr[i] + ky) * 10 + pc[i] + kx;
            abyte[i] = hp * 256;
            akey[i] = (hp & 7) << 4;
        }

        #pragma unroll
        for (int kk = 0; kk < 3; ++kk) {
            short8 b[3];
            #pragma unroll
            for (int n = 0; n < 3; ++n) {
                const int A = brow0 + n * 4096 + kk * 64;   // n*16 rows * 256 B
                b[n] = *(const short8*)((const char*)sWs + (A ^ bkey));
            }
            short8 a[4];
            #pragma unroll
            for (int i = 0; i < 4; ++i) {
                const int s = (kk * 64 + lq * 16) ^ akey[i];
                a[i] = *(const short8*)((const char*)sH + abyte[i] + s);
            }
            #pragma unroll
            for (int i = 0; i < 4; ++i)
                #pragma unroll
                for (int n = 0; n < 3; ++n)
                    acc[i][n] = __builtin_amdgcn_mfma_f32_16x16x32_bf16(
                        a[i], b[n], acc[i][n], 0, 0, 0);
        }
        __syncthreads();                 // all waves done reading sWs (+sH last tap)
        if (tap < 8) { stageW(tap + 1); __syncthreads(); }
    }

    // ---- epilogue: bias (exact, border-corrected) + silu + residual ----
    float* sY = (float*)sH;              // 64 px * 100 dw (sH dead)
    float bvn[3];
    #pragma unroll
    for (int n = 0; n < 3; ++n) bvn[n] = g_Ball[w * 48 + n * 16 + lm];

    const bool borderTile = (ty == 0) || (ty == 48) || (tx == 0) || (tx == 48);
    float bt[3][9];
    if (borderTile) {
        #pragma unroll
        for (int n = 0; n < 3; ++n)
            #pragma unroll
            for (int d2 = 0; d2 < 9; ++d2)
                bt[n][d2] = g_Bt[d2 * 96 + w * 48 + n * 16 + lm];
    }

    #pragma unroll
    for (int i = 0; i < 4; ++i)
        #pragma unroll
        for (int r4 = 0; r4 < 4; ++r4) {
            const int p = i * 16 + lq * 4 + r4;
            const int grow = ty + (p >> 3), gcol = tx + (p & 7);
            float corr[3] = {0.f, 0.f, 0.f};
            if (borderTile) {
                #pragma unroll
                for (int dy = 0; dy < 3; ++dy)
                    #pragma unroll
                    for (int dx = 0; dx < 3; ++dx) {
                        const int gr2 = grow + dy - 1, gc2 = gcol + dx - 1;
                        if (gr2 < 0 || gr2 >= HH || gc2 < 0 || gc2 >= WW) {
                            corr[0] += bt[0][dy * 3 + dx];
                            corr[1] += bt[1][dy * 3 + dx];
                            corr[2] += bt[2][dy * 3 + dx];
                        }
                    }
            }
            #pragma unroll
            for (int n = 0; n < 3; ++n) {
                const float y = acc[i][n][r4] + bvn[n] - corr[n];
                const float sig = 1.f / (1.f + __expf(-y));
                sY[p * 100 + w * 48 + n * 16 + lm] = y * sig;
            }
        }
    __syncthreads();

    #pragma unroll
    for (int c = 0; c < 12; ++c) {
        const int d = c * 512 + t * 4;                 // < 6144
        const int px = d / 96, b = d - px * 96;
        const int grow = ty + (px >> 3), gcol = tx + (px & 7);
        const size_t gdw = (imgbase + grow * WW + gcol) * 96 + b;
        const f32x4 yv = *(const f32x4*)(sY + px * 100 + b);
        const float4 xv = *(const float4*)(X + gdw);
        float4 o;
        o.x = xv.x + yv[0]; o.y = xv.y + yv[1];
        o.z = xv.z + yv[2]; o.w = xv.w + yv[3];
        *(float4*)(OUT + gdw) = o;
    }
}

extern "C" void kernel_launch(void* const* d_in, const int* in_sizes, int n_in,
                              void* d_out, int out_size, void* d_ws, size_t ws_size,
                              hipStream_t stream) {
    (void)in_sizes; (void)n_in; (void)out_size; (void)d_ws; (void)ws_size;
    const float* X    = (const float*)d_in[0];
    const float* ln_w = (const float*)d_in[1];
    const float* ln_b = (const float*)d_in[2];
    const float* Wi   = (const float*)d_in[3];
    const float* b_in = (const float*)d_in[4];
    const float* Wc   = (const float*)d_in[5];
    const float* cb   = (const float*)d_in[6];
    float* OUT = (float*)d_out;

    k0_wt<<<(9 * WSLAB + 960 + 255) / 256, 256, 0, stream>>>(Wc, Wi, b_in, cb);
    k_fused<<<K2_NWG, 128, 0, stream>>>(X, ln_w, ln_b, OUT);
}

// Round 29
// 72.649 us; speedup vs baseline: 2.4510x; 1.2778x over previous
//
#include <hip/hip_runtime.h>
#include <hip/hip_bf16.h>

#define D_MODEL 96
#define D_INNER 192
#define BATCH 32
#define HH 56
#define WW 56
#define NPIX (BATCH*HH*WW)   // 100352
#define LN_EPS 1e-5f
#define WSLAB 12288          // shorts per combined tap slab (96 oc * 128 pad)
#define WSLABB 24576         // bytes
#define K2_NWG 1568          // NPIX / 64 = 8 * 196 (bijective XCD swizzle)
#define K2_CPX 196

typedef unsigned short ushort_t;
typedef __attribute__((ext_vector_type(8))) short short8;   // 8 bf16 (4 VGPRs)
typedef __attribute__((ext_vector_type(4))) float f32x4;

// g_Wcomb[tap][oc][s]: combined (Wi_live @ Wc[tap]) bf16, 256-B rows,
// pre-swizzled by short-index XOR ((oc&7)<<3) (r27-verified).
// g_Bt[tap][oc] = b_in @ Wc[tap] (fp32). (Ball now computed in epilogue.)
__device__ __align__(16) ushort_t g_Wcomb[9 * WSLAB];
__device__ float g_Bt[9 * 96];

static __device__ __forceinline__ unsigned short f2bf(float f) {
    unsigned u = __float_as_uint(f);
    unsigned r = (u + 0x7fffu + ((u >> 16) & 1u)) >> 16;
    return (unsigned short)r;
}

// ---------------------------------------------------------------------------
// Kernel 0: weight fold (r27-verified math). ROUND-29: 4 independent
// accumulators per dot product (r28's serial FMA chain = 192 x 4 cy was the
// cost, not coalescing); g_Ball's 1728-MAC serial tail DELETED (computed in
// the fused epilogue from g_Bt + conv_b instead).
// ---------------------------------------------------------------------------
__global__ __launch_bounds__(256) void k0_wt(const float* __restrict__ Wc,
                                             const float* __restrict__ Wi,
                                             const float* __restrict__ b_in) {
    __shared__ float sWi[96 * 193];   // 74,112 B
    const int t = threadIdx.x;
    for (int i = t; i < 96 * 192; i += 256) {
        const int c = i / 192, j = i - c * 192;
        sWi[c * 193 + j] = Wi[c * 384 + j];
    }
    __syncthreads();

    const int o = blockIdx.x * 256 + t;
    if (o < 9 * WSLAB) {
        const int tap = o / WSLAB;
        const int rem = o - tap * WSLAB;
        const int oc = rem >> 7, s = rem & 127;
        const int sl = s ^ ((oc & 7) << 3);          // logical c index
        float acc = 0.f;
        if (sl < 96) {
            const float* wi = sWi + sl * 193;
            const float* wc = Wc + (size_t)tap * 18432 + oc;
            float a0 = 0.f, a1 = 0.f, a2 = 0.f, a3 = 0.f;
            #pragma unroll 8
            for (int j = 0; j < 192; j += 4) {
                a0 += wi[j + 0] * wc[(j + 0) * 96];
                a1 += wi[j + 1] * wc[(j + 1) * 96];
                a2 += wi[j + 2] * wc[(j + 2) * 96];
                a3 += wi[j + 3] * wc[(j + 3) * 96];
            }
            acc = (a0 + a1) + (a2 + a3);
        }
        g_Wcomb[o] = f2bf(acc);
    } else if (o < 9 * WSLAB + 864) {
        const int idx = o - 9 * WSLAB;
        const int tap = idx / 96, oc = idx - tap * 96;
        const float* wc = Wc + (size_t)tap * 18432 + oc;
        float a0 = 0.f, a1 = 0.f, a2 = 0.f, a3 = 0.f;
        #pragma unroll 8
        for (int j = 0; j < 192; j += 4) {
            a0 += b_in[j + 0] * wc[(j + 0) * 96];
            a1 += b_in[j + 1] * wc[(j + 1) * 96];
            a2 += b_in[j + 2] * wc[(j + 2) * 96];
            a3 += b_in[j + 3] * wc[(j + 3) * 96];
        }
        g_Bt[idx] = (a0 + a1) + (a2 + a3);
    }
}

// ---------------------------------------------------------------------------
// FUSED kernel: LN (halo recompute) + folded conv + bias + SiLU + residual.
// r28-verified structure; ONLY epilogue bias source changed: bvn computed
// inline as conv_b[oc] + sum_tap g_Bt[tap][oc] (algebraically = old g_Ball).
// ---------------------------------------------------------------------------
__global__ __launch_bounds__(128) void k_fused(
    const float* __restrict__ X, const float* __restrict__ ln_w,
    const float* __restrict__ ln_b, const float* __restrict__ conv_b,
    float* __restrict__ OUT)
{
    __shared__ ushort_t sH[100 * 128];   // 25,600 B halo h (swizzled rows)
    __shared__ ushort_t sWs[WSLAB];      // 24,576 B tap slab (pre-swizzled)
    const int t = threadIdx.x;
    const int w = t >> 6, l = t & 63;
    const int lm = l & 15, lq = l >> 4;

    const int lb = ((int)blockIdx.x & 7) * K2_CPX + ((int)blockIdx.x >> 3);
    const int img = lb / 49, tile = lb - img * 49;
    const int ty = (tile / 7) * 8, tx = (tile % 7) * 8;
    const size_t imgbase = (size_t)img * 3136;

    // ---- W staging: linear async copy (r27-verified) ----
    auto stageW = [&](int tap) {
        const char* g = (const char*)g_Wcomb + (size_t)tap * WSLABB + t * 16;
        char* d = (char*)sWs + t * 16;
        #pragma unroll
        for (int j = 0; j < 12; ++j)
            __builtin_amdgcn_global_load_lds(
                (const __attribute__((address_space(1))) unsigned*)(g + j * 2048),
                (__attribute__((address_space(3))) unsigned*)(d + j * 2048),
                16, 0, 0);
    };
    stageW(0);                           // overlaps Phase-1 LN

    // ================= Phase 1: LN halo -> swizzled sH ====================
    {
        const int g4 = t >> 2, tig = t & 3;
        #pragma unroll 1
        for (int it = 0; it < 4; ++it) {
            const int px = it * 32 + g4;
            if (px >= 100) continue;
            const int hr = px / 10, hc = px - hr * 10;
            const int gr = ty + hr - 1, gc = tx + hc - 1;
            const bool valid = gr >= 0 && gr < HH && gc >= 0 && gc < WW;
            const float* xp = X + (imgbase + gr * WW + gc) * 96 + tig * 24;
            uint4 out[3];
            if (valid) {
                float4 xq[6];
                float s = 0.f;
                #pragma unroll
                for (int c = 0; c < 6; ++c) {
                    xq[c] = *(const float4*)(xp + c * 4);
                    s += xq[c].x + xq[c].y + xq[c].z + xq[c].w;
                }
                s += __shfl_xor(s, 1, 4);
                s += __shfl_xor(s, 2, 4);
                const float mu = s * (1.f / 96.f);
                float v = 0.f;
                #pragma unroll
                for (int c = 0; c < 6; ++c) {
                    const float d0 = xq[c].x - mu, d1 = xq[c].y - mu;
                    const float d2 = xq[c].z - mu, d3 = xq[c].w - mu;
                    v += d0 * d0 + d1 * d1 + d2 * d2 + d3 * d3;
                }
                v += __shfl_xor(v, 1, 4);
                v += __shfl_xor(v, 2, 4);
                const float rs = rsqrtf(v * (1.f / 96.f) + LN_EPS);
                unsigned u[12];
                #pragma unroll
                for (int c = 0; c < 6; ++c) {
                    const float4 lw = *(const float4*)(ln_w + tig * 24 + c * 4);
                    const float4 lb2 = *(const float4*)(ln_b + tig * 24 + c * 4);
                    u[c * 2 + 0] = (unsigned)f2bf((xq[c].x - mu) * rs * lw.x + lb2.x)
                                 | ((unsigned)f2bf((xq[c].y - mu) * rs * lw.y + lb2.y) << 16);
                    u[c * 2 + 1] = (unsigned)f2bf((xq[c].z - mu) * rs * lw.z + lb2.z)
                                 | ((unsigned)f2bf((xq[c].w - mu) * rs * lw.w + lb2.w) << 16);
                }
                out[0] = make_uint4(u[0], u[1], u[2], u[3]);
                out[1] = make_uint4(u[4], u[5], u[6], u[7]);
                out[2] = make_uint4(u[8], u[9], u[10], u[11]);
            } else {
                out[0] = out[1] = out[2] = make_uint4(0u, 0u, 0u, 0u);
            }
            const int key = (px & 7) << 4;
            char* rowp = (char*)sH + px * 256;
            #pragma unroll
            for (int q = 0; q < 3; ++q)
                *(uint4*)(rowp + (((tig * 3 + q) * 16) ^ key)) = out[q];
        }
    }
    __syncthreads();   // sH written + tap-0 slab drained (vmcnt)

    // ========== Phase 2: conv main loop (byte-identical to r27/r28) =======
    int pr[4], pc[4];
    #pragma unroll
    for (int i = 0; i < 4; ++i) {
        const int px = i * 16 + lm;
        pr[i] = px >> 3; pc[i] = px & 7;
    }

    f32x4 acc[4][3];
    const f32x4 zf = {0.f, 0.f, 0.f, 0.f};
    #pragma unroll
    for (int i = 0; i < 4; ++i)
        #pragma unroll
        for (int n = 0; n < 3; ++n) acc[i][n] = zf;

    const int bkey = (lm & 7) << 4;
    const int brow0 = (w * 48 + lm) * 256 + lq * 16;   // wave's oc base row

    #pragma unroll 1
    for (int tap = 0; tap < 9; ++tap) {
        const int ky = tap / 3, kx = tap - (tap / 3) * 3;
        int abyte[4], akey[4];
        #pragma unroll
        for (int i = 0; i < 4; ++i) {
            const int hp = (pr[i] + ky) * 10 + pc[i] + kx;
            abyte[i] = hp * 256;
            akey[i] = (hp & 7) << 4;
        }

        #pragma unroll
        for (int kk = 0; kk < 3; ++kk) {
            short8 b[3];
            #pragma unroll
            for (int n = 0; n < 3; ++n) {
                const int A = brow0 + n * 4096 + kk * 64;   // n*16 rows * 256 B
                b[n] = *(const short8*)((const char*)sWs + (A ^ bkey));
            }
            short8 a[4];
            #pragma unroll
            for (int i = 0; i < 4; ++i) {
                const int s = (kk * 64 + lq * 16) ^ akey[i];
                a[i] = *(const short8*)((const char*)sH + abyte[i] + s);
            }
            #pragma unroll
            for (int i = 0; i < 4; ++i)
                #pragma unroll
                for (int n = 0; n < 3; ++n)
                    acc[i][n] = __builtin_amdgcn_mfma_f32_16x16x32_bf16(
                        a[i], b[n], acc[i][n], 0, 0, 0);
        }
        __syncthreads();                 // all waves done reading sWs (+sH last tap)
        if (tap < 8) { stageW(tap + 1); __syncthreads(); }
    }

    // ---- epilogue: bias (conv_b + sum Bt, border-corrected) + silu ----
    float* sY = (float*)sH;              // 64 px * 100 dw (sH dead)
    float bt[3][9];
    #pragma unroll
    for (int n = 0; n < 3; ++n)
        #pragma unroll
        for (int d2 = 0; d2 < 9; ++d2)
            bt[n][d2] = g_Bt[d2 * 96 + w * 48 + n * 16 + lm];
    float bvn[3];
    #pragma unroll
    for (int n = 0; n < 3; ++n) {
        float sum = conv_b[w * 48 + n * 16 + lm];
        #pragma unroll
        for (int d2 = 0; d2 < 9; ++d2) sum += bt[n][d2];
        bvn[n] = sum;
    }

    const bool borderTile = (ty == 0) || (ty == 48) || (tx == 0) || (tx == 48);

    #pragma unroll
    for (int i = 0; i < 4; ++i)
        #pragma unroll
        for (int r4 = 0; r4 < 4; ++r4) {
            const int p = i * 16 + lq * 4 + r4;
            const int grow = ty + (p >> 3), gcol = tx + (p & 7);
            float corr[3] = {0.f, 0.f, 0.f};
            if (borderTile) {
                #pragma unroll
                for (int dy = 0; dy < 3; ++dy)
                    #pragma unroll
                    for (int dx = 0; dx < 3; ++dx) {
                        const int gr2 = grow + dy - 1, gc2 = gcol + dx - 1;
                        if (gr2 < 0 || gr2 >= HH || gc2 < 0 || gc2 >= WW) {
                            corr[0] += bt[0][dy * 3 + dx];
                            corr[1] += bt[1][dy * 3 + dx];
                            corr[2] += bt[2][dy * 3 + dx];
                        }
                    }
            }
            #pragma unroll
            for (int n = 0; n < 3; ++n) {
                const float y = acc[i][n][r4] + bvn[n] - corr[n];
                const float sig = 1.f / (1.f + __expf(-y));
                sY[p * 100 + w * 48 + n * 16 + lm] = y * sig;
            }
        }
    __syncthreads();

    #pragma unroll
    for (int c = 0; c < 12; ++c) {
        const int d = c * 512 + t * 4;                 // < 6144
        const int px = d / 96, b = d - px * 96;
        const int grow = ty + (px >> 3), gcol = tx + (px & 7);
        const size_t gdw = (imgbase + grow * WW + gcol) * 96 + b;
        const f32x4 yv = *(const f32x4*)(sY + px * 100 + b);
        const float4 xv = *(const float4*)(X + gdw);
        float4 o;
        o.x = xv.x + yv[0]; o.y = xv.y + yv[1];
        o.z = xv.z + yv[2]; o.w = xv.w + yv[3];
        *(float4*)(OUT + gdw) = o;
    }
}

extern "C" void kernel_launch(void* const* d_in, const int* in_sizes, int n_in,
                              void* d_out, int out_size, void* d_ws, size_t ws_size,
                              hipStream_t stream) {
    (void)in_sizes; (void)n_in; (void)out_size; (void)d_ws; (void)ws_size;
    const float* X    = (const float*)d_in[0];
    const float* ln_w = (const float*)d_in[1];
    const float* ln_b = (const float*)d_in[2];
    const float* Wi   = (const float*)d_in[3];
    const float* b_in = (const float*)d_in[4];
    const float* Wc   = (const float*)d_in[5];
    const float* cb   = (const float*)d_in[6];
    float* OUT = (float*)d_out;

    k0_wt<<<(9 * WSLAB + 864 + 255) / 256, 256, 0, stream>>>(Wc, Wi, b_in);
    k_fused<<<K2_NWG, 128, 0, stream>>>(X, ln_w, ln_b, cb, OUT);
}